// Round 1
// baseline (650.011 us; speedup 1.0000x reference)
//
#include <hip/hip_runtime.h>
#include <hip/hip_bf16.h>
#include <math.h>

// Shapes (fixed by the problem)
#define Bb 2
#define Ss 8192
#define Cc 1536
#define Pp 512
#define Hh 32
#define Ff 128
#define HF 4096   // H*F

typedef short s8v __attribute__((ext_vector_type(8)));
typedef float f4v __attribute__((ext_vector_type(4)));

__device__ __forceinline__ ushort f2bf(float f) {
  union { float f; unsigned u; } v; v.f = f;
  unsigned r = v.u + 0x7FFFu + ((v.u >> 16) & 1u);
  return (ushort)(r >> 16);
}
__device__ __forceinline__ float bf2f(ushort s) {
  union { unsigned u; float f; } v; v.u = ((unsigned)s) << 16; return v.f;
}

// ---------------- K0: fp32 [R][Cn] -> bf16 [Cn][R] transpose ----------------
__global__ __launch_bounds__(256) void transpose_to_bf16(
    const float* __restrict__ in, ushort* __restrict__ out, int R, int Cn) {
  __shared__ float tile[32][33];
  int c0 = blockIdx.x * 32, r0 = blockIdx.y * 32;
  int tc = threadIdx.x & 31, tr = threadIdx.x >> 5;   // tr 0..7
  #pragma unroll
  for (int i = 0; i < 4; ++i)
    tile[tr + i * 8][tc] = in[(long)(r0 + tr + i * 8) * Cn + c0 + tc];
  __syncthreads();
  #pragma unroll
  for (int i = 0; i < 4; ++i)
    out[(long)(c0 + tr + i * 8) * R + r0 + tc] = f2bf(tile[tc][tr + i * 8]);
}

// ---------------- K0b: pos_enc = 0.25*(pos_feat @ Wpos + bpos), bf16 [1024][4096]
__global__ __launch_bounds__(256) void posenc_kernel(
    const float* __restrict__ Wpos, const float* __restrict__ bpos,
    ushort* __restrict__ pe) {
  __shared__ float suf[17][256];
  __shared__ float sufd[17][256];
  __shared__ float cws[16];
  int t = threadIdx.x;
  int hf = blockIdx.x * 256 + t;
  int p0 = blockIdx.y * 64;
  if (t < 16) {
    double geo = pow(10.0, (double)t * log10(497.0) / 16.0);
    cws[t] = (float)t + (float)geo;   // widths_lin + widths_geo (f32, matches np)
  }
  float s1 = 0.f, s2 = 0.f;
  suf[16][t] = 0.f; sufd[16][t] = 0.f;
  #pragma unroll
  for (int i = 15; i >= 0; --i) {
    s1 += Wpos[i * HF + hf];
    s2 += Wpos[(16 + i) * HF + hf];
    suf[i][t] = s1; sufd[i][t] = s2;
  }
  float bp = bpos[hf];
  __syncthreads();
  for (int pi = 0; pi < 64; ++pi) {
    int p = p0 + pi;
    int rel = p - Pp;
    float a = fabsf((float)rel);
    float sg = (rel > 0) ? 1.f : ((rel < 0) ? -1.f : 0.f);
    int th = 0;
    #pragma unroll
    for (int i = 0; i < 16; ++i) th += (cws[i] <= a) ? 1 : 0;  // onehot true for i>=th
    float val = 0.25f * (suf[th][t] + sg * sufd[th][t] + bp);
    pe[(long)p * HF + hf] = f2bf(val);
  }
}

// ---------------- K1: window mean-pool + RMSNorm + gelu -> xn,xg bf16 [1024][1536]
__global__ __launch_bounds__(256) void pool_norm_kernel(
    const float* __restrict__ x, const float* __restrict__ norm_w,
    ushort* __restrict__ xn, ushort* __restrict__ xg) {
  int bp = blockIdx.x, t = threadIdx.x;
  const float* xr = x + (long)bp * 16 * Cc;
  float v[6];
  float ss = 0.f;
  #pragma unroll
  for (int j = 0; j < 6; ++j) {
    int c = j * 256 + t;
    float s = 0.f;
    #pragma unroll
    for (int r = 0; r < 16; ++r) s += xr[r * Cc + c];
    v[j] = s * 0.0625f;
    ss += v[j] * v[j];
  }
  #pragma unroll
  for (int off = 32; off; off >>= 1) ss += __shfl_down(ss, off);
  __shared__ float red[4];
  int w = t >> 6, lane = t & 63;
  if (lane == 0) red[w] = ss;
  __syncthreads();
  float tot = red[0] + red[1] + red[2] + red[3];
  float rs = 1.0f / sqrtf(tot * (1.0f / 1536.0f) + 1e-8f);
  #pragma unroll
  for (int j = 0; j < 6; ++j) {
    int c = j * 256 + t;
    float xnf = v[j] * rs * norm_w[c];
    xn[(long)bp * Cc + c] = f2bf(xnf);
    float g = 0.5f * xnf * (1.0f + erff(xnf * 0.70710678118654752f));
    xg[(long)bp * Cc + c] = f2bf(g);
  }
}

// ---------------- K2: generic bf16 MFMA GEMM, A [M,K] row-major, B^T [N,K] row-major
// EPI 0: bf16 store, 1: f32 store, 2: banded bf16 store (rel-shift band)
template <int EPI>
__global__ __launch_bounds__(256) void gemm_bt(
    const ushort* __restrict__ A, const ushort* __restrict__ B, void* __restrict__ C,
    const float* __restrict__ bias,
    int M, int N, int K, int lda, int ldb, int ldc,
    long sAz, long sBz, long sCz, int sBiasz) {
  __shared__ ushort As[64 * 40];
  __shared__ ushort Bs[64 * 40];
  int m0 = blockIdx.y * 64, n0 = blockIdx.x * 64;
  if (EPI == 2) {
    // band tiles only: needed p in [449-q0r, 1023-q0r]
    int q0r = m0 & (Pp - 1);
    if (n0 + 63 < 449 - q0r || n0 > 1023 - q0r) return;
  }
  int z = blockIdx.z;
  const ushort* Az = A + (long)z * sAz;
  const ushort* Bz = B + (long)z * sBz;
  const float* biasz = bias ? (bias + (long)z * sBiasz) : nullptr;
  int t = threadIdx.x;
  int trow = t >> 2, tcol = (t & 3) * 8;
  int w = t >> 6, lane = t & 63, l15 = lane & 15, quad = lane >> 4;
  int mw = (w & 1) * 32, nw = (w >> 1) * 32;
  f4v acc[2][2] = {};
  int nk = K >> 5;
  for (int kt = 0; kt < nk; ++kt) {
    int k0 = kt << 5;
    __syncthreads();
    s8v av = *(const s8v*)(Az + (long)(m0 + trow) * lda + k0 + tcol);
    s8v bv = *(const s8v*)(Bz + (long)(n0 + trow) * ldb + k0 + tcol);
    if (biasz) {
      ushort* ap = (ushort*)&av;
      #pragma unroll
      for (int j = 0; j < 8; ++j) ap[j] = f2bf(bf2f(ap[j]) + biasz[k0 + tcol + j]);
    }
    *(s8v*)&As[trow * 40 + tcol] = av;
    *(s8v*)&Bs[trow * 40 + tcol] = bv;
    __syncthreads();
    s8v a0 = *(const s8v*)&As[(mw + l15) * 40 + quad * 8];
    s8v a1 = *(const s8v*)&As[(mw + 16 + l15) * 40 + quad * 8];
    s8v b0 = *(const s8v*)&Bs[(nw + l15) * 40 + quad * 8];
    s8v b1 = *(const s8v*)&Bs[(nw + 16 + l15) * 40 + quad * 8];
    acc[0][0] = __builtin_amdgcn_mfma_f32_16x16x32_bf16(a0, b0, acc[0][0], 0, 0, 0);
    acc[0][1] = __builtin_amdgcn_mfma_f32_16x16x32_bf16(a0, b1, acc[0][1], 0, 0, 0);
    acc[1][0] = __builtin_amdgcn_mfma_f32_16x16x32_bf16(a1, b0, acc[1][0], 0, 0, 0);
    acc[1][1] = __builtin_amdgcn_mfma_f32_16x16x32_bf16(a1, b1, acc[1][1], 0, 0, 0);
  }
  #pragma unroll
  for (int mt = 0; mt < 2; ++mt)
    #pragma unroll
    for (int nt = 0; nt < 2; ++nt)
      #pragma unroll
      for (int r = 0; r < 4; ++r) {
        int gm = m0 + mw + mt * 16 + quad * 4 + r;   // C/D: row = quad*4+reg
        int gn = n0 + nw + nt * 16 + l15;            //      col = lane&15
        float val = acc[mt][nt][r];
        if (EPI == 0) {
          ((ushort*)C)[(long)z * sCz + (long)gm * ldc + gn] = f2bf(val);
        } else if (EPI == 1) {
          ((float*)C)[(long)z * sCz + (long)gm * ldc + gn] = val;
        } else {
          int bb = gm >> 9, qrow = gm & (Pp - 1);
          int jj = gn + qrow - Pp;                   // band index = k
          if ((unsigned)jj < (unsigned)Pp)
            ((ushort*)C)[(long)bb * (Hh * (long)Pp * Pp) + (long)z * sCz +
                         (long)qrow * Pp + jj] = f2bf(val);
        }
      }
}

// ---------------- K3: fused pair kernel ----------------
// per 16x16 (q,k) tile: a[q,k,h] = QK^T + RQband[q,k] + RKband[k,q]  (32 heads)
// then pair[q,k,:] = a @ Wout + bout + y_q[q,:] + y_k[k,:]
__global__ __launch_bounds__(256) void pair_kernel(
    const ushort* __restrict__ qb, const ushort* __restrict__ kb,
    const ushort* __restrict__ RQb, const ushort* __restrict__ RKb,
    const float* __restrict__ Wout, const float* __restrict__ bout,
    const float* __restrict__ yq, const float* __restrict__ yk,
    float* __restrict__ out) {
  __shared__ ushort A2[256 * 40];    // [m=(qi*16+ki)][h], padded to 40
  __shared__ ushort WS[32 * 136];    // Wout bf16 [h][f], padded
  int t = threadIdx.x;
  int w = t >> 6, lane = t & 63, l15 = lane & 15, quad = lane >> 4;
  int k0 = blockIdx.x * 16, q0 = blockIdx.y * 16, b = blockIdx.z;

  #pragma unroll
  for (int j = 0; j < 16; ++j) {
    int idx = j * 256 + t;
    WS[(idx >> 7) * 136 + (idx & 127)] = f2bf(Wout[idx]);
  }
  float boutv[8];
  #pragma unroll
  for (int ft = 0; ft < 8; ++ft) boutv[ft] = bout[ft * 16 + l15];

  // phase 1: S_h = Q K^T + bands, scattered into A2 (A-operand layout for phase 2)
  for (int i = 0; i < 8; ++i) {
    int h = w * 8 + i;
    const ushort* qp = qb + (long)(b * Pp + q0 + l15) * HF + h * Ff + quad * 8;
    const ushort* kp = kb + (long)(b * Pp + k0 + l15) * HF + h * Ff + quad * 8;
    f4v acc = {};
    #pragma unroll
    for (int ks = 0; ks < 4; ++ks) {
      s8v aq = *(const s8v*)(qp + ks * 32);
      s8v bk = *(const s8v*)(kp + ks * 32);
      acc = __builtin_amdgcn_mfma_f32_16x16x32_bf16(aq, bk, acc, 0, 0, 0);
    }
    long rqbase = ((long)(b * Hh + h) * Pp + q0) * Pp + k0;
    long rkbase = ((long)(b * Hh + h) * Pp + k0) * Pp + q0;
    #pragma unroll
    for (int r = 0; r < 4; ++r) {
      int row = quad * 4 + r;   // local q
      float v = acc[r] + bf2f(RQb[rqbase + (long)row * Pp + l15])
                       + bf2f(RKb[rkbase + (long)l15 * Pp + row]);
      A2[(row * 16 + l15) * 40 + h] = f2bf(v);
    }
  }
  __syncthreads();

  // phase 2: pair = A2 @ Wout + bout + y_q + y_k
  s8v wfr[8];
  #pragma unroll
  for (int ft = 0; ft < 8; ++ft) {
    ushort* wp = (ushort*)&wfr[ft];
    #pragma unroll
    for (int j = 0; j < 8; ++j) wp[j] = WS[(quad * 8 + j) * 136 + ft * 16 + l15];
  }
  #pragma unroll
  for (int qq = 0; qq < 4; ++qq) {
    int qi = w * 4 + qq;
    s8v afr = *(const s8v*)&A2[(qi * 16 + l15) * 40 + quad * 8];
    long yqbase = (long)(b * Pp + q0 + qi) * Ff;
    long obase = ((long)(b * Pp + q0 + qi) * Pp + k0) * (long)Ff;
    #pragma unroll
    for (int ft = 0; ft < 8; ++ft) {
      f4v d = {};
      d = __builtin_amdgcn_mfma_f32_16x16x32_bf16(afr, wfr[ft], d, 0, 0, 0);
      int f = ft * 16 + l15;
      float yqv = yq[yqbase + f] + boutv[ft];
      #pragma unroll
      for (int r = 0; r < 4; ++r) {
        int ki = quad * 4 + r;
        float ykv = yk[(long)(b * Pp + k0 + ki) * Ff + f];
        out[obase + (long)ki * Ff + f] = d[r] + yqv + ykv;
      }
    }
  }
}

extern "C" void kernel_launch(void* const* d_in, const int* in_sizes, int n_in,
                              void* d_out, int out_size, void* d_ws, size_t ws_size,
                              hipStream_t stream) {
  const float* x      = (const float*)d_in[0];
  const float* norm_w = (const float*)d_in[1];
  const float* Wq     = (const float*)d_in[2];
  const float* Wk     = (const float*)d_in[3];
  const float* Wpos   = (const float*)d_in[4];
  const float* bpos   = (const float*)d_in[5];
  const float* qrb    = (const float*)d_in[6];
  const float* krb    = (const float*)d_in[7];
  const float* Wyq    = (const float*)d_in[8];
  const float* Wyk    = (const float*)d_in[9];
  const float* Wout   = (const float*)d_in[10];
  const float* bout   = (const float*)d_in[11];
  float* out = (float*)d_out;

  char* ws = (char*)d_ws;
  size_t off = 0;
  auto alloc = [&](size_t bytes) {
    char* p = ws + off;
    off += (bytes + 255) & ~(size_t)255;
    return p;
  };
  ushort* xn   = (ushort*)alloc(1024L * Cc * 2);
  ushort* xg   = (ushort*)alloc(1024L * Cc * 2);
  ushort* WqkT = (ushort*)alloc(2L * HF * Cc * 2);      // WqT then WkT
  ushort* WyT  = (ushort*)alloc(2L * Ff * Cc * 2);      // WyqT then WykT
  ushort* pe   = (ushort*)alloc(1024L * HF * 2);        // pos_enc (0.25-scaled)
  ushort* qk   = (ushort*)alloc(2L * 1024 * HF * 2);    // q then k, bf16
  float*  y2   = (float*)alloc(2L * 1024 * Ff * 4);     // y_q then y_k
  ushort* RQb  = (ushort*)alloc((long)Bb * Hh * Pp * Pp * 2);
  ushort* RKb  = (ushort*)alloc((long)Bb * Hh * Pp * Pp * 2);

  transpose_to_bf16<<<dim3(HF / 32, Cc / 32), 256, 0, stream>>>(Wq, WqkT, Cc, HF);
  transpose_to_bf16<<<dim3(HF / 32, Cc / 32), 256, 0, stream>>>(Wk, WqkT + (long)HF * Cc, Cc, HF);
  transpose_to_bf16<<<dim3(Ff / 32, Cc / 32), 256, 0, stream>>>(Wyq, WyT, Cc, Ff);
  transpose_to_bf16<<<dim3(Ff / 32, Cc / 32), 256, 0, stream>>>(Wyk, WyT + (long)Ff * Cc, Cc, Ff);
  posenc_kernel<<<dim3(16, 16), 256, 0, stream>>>(Wpos, bpos, pe);
  pool_norm_kernel<<<1024, 256, 0, stream>>>(x, norm_w, xn, xg);
  // q,k projections (z: 0=q, 1=k)
  gemm_bt<0><<<dim3(64, 16, 2), 256, 0, stream>>>(
      xn, WqkT, qk, nullptr, 1024, HF, Cc, Cc, Cc, HF,
      0L, (long)HF * Cc, 1024L * HF, 0);
  // y_q, y_k
  gemm_bt<1><<<dim3(2, 16, 2), 256, 0, stream>>>(
      xg, WyT, y2, nullptr, 1024, Ff, Cc, Cc, Cc, Ff,
      0L, (long)Ff * Cc, 1024L * Ff, 0);
  // banded RQ / RK (z = head)
  gemm_bt<2><<<dim3(16, 16, 32), 256, 0, stream>>>(
      qk, pe, RQb, qrb, 1024, 1024, Ff, HF, HF, 0,
      (long)Ff, (long)Ff, (long)Pp * Pp, Ff);
  gemm_bt<2><<<dim3(16, 16, 32), 256, 0, stream>>>(
      qk + 1024L * HF, pe, RKb, krb, 1024, 1024, Ff, HF, HF, 0,
      (long)Ff, (long)Ff, (long)Pp * Pp, Ff);
  // fused pair
  pair_kernel<<<dim3(Pp / 16, Pp / 16, Bb), 256, 0, stream>>>(
      qk, qk + 1024L * HF, RQb, RKb, Wout, bout, y2, y2 + 1024L * Ff, out);
}